// Round 5
// baseline (358.877 us; speedup 1.0000x reference)
//
#include <hip/hip_runtime.h>
#include <math.h>

#define N_NODES 50000
#define HC1 256      // 4 heads * 64 ch
#define H1 4
#define C2 40
#define C2P 64       // padded
#define E0 800000
#define ET 850000
#define NEG_SLOPE 0.2f
#define EPS_A 1e-16f

typedef __bf16 bf16x8 __attribute__((ext_vector_type(8)));
typedef float f32x4 __attribute__((ext_vector_type(4)));
typedef unsigned short u16x8 __attribute__((ext_vector_type(8)));

// ---------------- bf16 helpers (RNE) ----------------

__device__ inline unsigned short f2bf(float f) {
    unsigned u = __float_as_uint(f);
    return (unsigned short)((u + 0x7FFFu + ((u >> 16) & 1u)) >> 16);
}
__device__ inline float bf_lo(unsigned q) { return __uint_as_float(q << 16); }
__device__ inline float bf_hi(unsigned q) { return __uint_as_float(q & 0xFFFF0000u); }

// ---------------- utility ----------------

__device__ inline int edge_src(const int* __restrict__ ei, int e) {
    return (e < E0) ? ei[e] : (e - E0);
}
__device__ inline int edge_dst(const int* __restrict__ ei, int e) {
    return (e < E0) ? ei[E0 + e] : (e - E0);
}

// 8-channel bf16-pair FMA accumulate
__device__ inline void acc8(float ac[8], float A, uint4 q) {
    ac[0] += A * bf_lo(q.x); ac[1] += A * bf_hi(q.x);
    ac[2] += A * bf_lo(q.y); ac[3] += A * bf_hi(q.y);
    ac[4] += A * bf_lo(q.z); ac[5] += A * bf_hi(q.z);
    ac[6] += A * bf_lo(q.w); ac[7] += A * bf_hi(q.w);
}

__device__ inline float leaky(float v) { return v > 0.f ? v : NEG_SLOPE * v; }

// ------- merged prep: x -> bf16, W1^T -> bf16, W2^T(padded) -> bf16, deg = 0 -------

#define CV_X 3200000          // float4 groups of x
#define CV_W1 65536
#define CV_W2 16384
#define CV_TOT (CV_X + CV_W1 + CV_W2 + N_NODES)

__global__ void convert_all_kernel(const float* __restrict__ x,
                                   const float* __restrict__ W1,
                                   const float* __restrict__ W2,
                                   ushort4* __restrict__ xbf,
                                   unsigned short* __restrict__ w1t,
                                   unsigned short* __restrict__ w2t,
                                   int* __restrict__ deg) {
    int tid = blockIdx.x * blockDim.x + threadIdx.x;
    if (tid < CV_X) {
        float4 v = ((const float4*)x)[tid];
        ushort4 w;
        w.x = f2bf(v.x); w.y = f2bf(v.y); w.z = f2bf(v.z); w.w = f2bf(v.w);
        xbf[tid] = w;
    } else if (tid < CV_X + CV_W1) {
        int i = tid - CV_X;
        int n = i >> 8, k = i & 255;
        w1t[i] = f2bf(W1[k * 256 + n]);
    } else if (tid < CV_X + CV_W1 + CV_W2) {
        int i = tid - CV_X - CV_W1;
        int n = i >> 8, k = i & 255;
        w2t[i] = (n < C2) ? f2bf(W2[k * C2 + n]) : (unsigned short)0;
    } else if (tid < CV_TOT) {
        deg[tid - CV_X - CV_W1 - CV_W2] = 0;
    }
}

// ---------------- CSR build ----------------

__global__ void hist_kernel(const int* __restrict__ ei, int* __restrict__ deg) {
    int e = blockIdx.x * blockDim.x + threadIdx.x;
    if (e >= ET) return;
    atomicAdd(&deg[edge_dst(ei, e)], 1);
}

__global__ __launch_bounds__(256) void scan_block_kernel(const int* __restrict__ deg,
                                                         int* __restrict__ excl,
                                                         int* __restrict__ bsum) {
    __shared__ int tmp[256];
    int t = threadIdx.x;
    int i = blockIdx.x * 256 + t;
    int v = (i < N_NODES) ? deg[i] : 0;
    tmp[t] = v;
    __syncthreads();
#pragma unroll
    for (int o = 1; o < 256; o <<= 1) {
        int x = (t >= o) ? tmp[t - o] : 0;
        __syncthreads();
        tmp[t] += x;
        __syncthreads();
    }
    if (i < N_NODES) excl[i] = tmp[t] - v;
    if (t == 255) bsum[blockIdx.x] = tmp[255];
}

#define NSCAN_B 196   // ceil(50000/256)

__global__ __launch_bounds__(256) void scan_top_kernel(int* __restrict__ bsum) {
    __shared__ int tmp[256];
    int t = threadIdx.x;
    int v = (t < NSCAN_B) ? bsum[t] : 0;
    tmp[t] = v;
    __syncthreads();
#pragma unroll
    for (int o = 1; o < 256; o <<= 1) {
        int x = (t >= o) ? tmp[t - o] : 0;
        __syncthreads();
        tmp[t] += x;
        __syncthreads();
    }
    if (t < NSCAN_B) bsum[t] = tmp[t] - v;   // exclusive
}

__global__ __launch_bounds__(256) void scan_add_kernel(int* __restrict__ offsets,
                                                       int* __restrict__ cursor,
                                                       const int* __restrict__ bsum) {
    int i = blockIdx.x * 256 + threadIdx.x;
    if (i < N_NODES) {
        int v = offsets[i] + bsum[blockIdx.x];
        offsets[i] = v;
        cursor[i] = v;
    }
    if (i == 0) offsets[N_NODES] = ET;
}

// writes (edge id, src id) as one int2 in CSR order
__global__ void scatter_kernel(const int* __restrict__ ei, int* __restrict__ cursor,
                               int2* __restrict__ csr_es) {
    int e = blockIdx.x * blockDim.x + threadIdx.x;
    if (e >= ET) return;
    int d = edge_dst(ei, e);
    int pos = atomicAdd(&cursor[d], 1);
    csr_es[pos] = make_int2(e, edge_src(ei, e));
}

// ---------------- MFMA GEMM + attention-dot epilogue ----------------
// Cbf[M,Nc] = bf16( Abf[M,256] * Bt[Nc,256]^T ); K = 256.
// Epilogue: a_src_o[row*hstride+head] = sum_col acc*att_s[col] (head = wave col-base/64).
// Wave tile 64x64 (4x4 of 16x16x32 mfma). LDS stride 40 bf16 -> 2-way aliasing (free).

template <int TBM, int TBN, int WROWS, int WCOLS>
__global__ __launch_bounds__(256) void gemm_mfma_kernel(const unsigned short* __restrict__ Abf,
                                                        const unsigned short* __restrict__ Bt,
                                                        unsigned short* __restrict__ Cbf,
                                                        const float* __restrict__ att_s,
                                                        const float* __restrict__ att_d,
                                                        float* __restrict__ a_src_o,
                                                        float* __restrict__ a_dst_o,
                                                        int M, int Nc, int attN, int hstride) {
    static_assert(TBM == WROWS * 64 && TBN == WCOLS * 64, "tile");
    constexpr int LDK = 40;
    __shared__ alignas(16) unsigned short As[TBM * LDK];
    __shared__ alignas(16) unsigned short Bs[TBN * LDK];
    const int t = threadIdx.x;
    const int lane = t & 63;
    const int w = t >> 6;
    const int quad = lane >> 4;
    const int l16 = lane & 15;
    const int wm = (w / WCOLS) * 64;
    const int wn = (w % WCOLS) * 64;
    const int bm = blockIdx.x * TBM;
    const int bn = blockIdx.y * TBN;

    f32x4 acc[4][4] = {};

    for (int k0 = 0; k0 < 256; k0 += 32) {
        __syncthreads();
#pragma unroll
        for (int i = 0; i < TBM / 64; ++i) {
            int idx = t + i * 256;
            int row = idx >> 2, seg = idx & 3;
            u16x8 v = {};
            if (bm + row < M)
                v = *(const u16x8*)(Abf + (size_t)(bm + row) * 256 + k0 + seg * 8);
            *(u16x8*)&As[row * LDK + seg * 8] = v;
        }
#pragma unroll
        for (int i = 0; i < TBN / 64; ++i) {
            int idx = t + i * 256;
            int row = idx >> 2, seg = idx & 3;
            u16x8 v = *(const u16x8*)(Bt + (size_t)(bn + row) * 256 + k0 + seg * 8);
            *(u16x8*)&Bs[row * LDK + seg * 8] = v;
        }
        __syncthreads();

        bf16x8 af[4], bfr[4];
#pragma unroll
        for (int mi = 0; mi < 4; ++mi)
            af[mi] = *(const bf16x8*)&As[(wm + mi * 16 + l16) * LDK + quad * 8];
#pragma unroll
        for (int ni = 0; ni < 4; ++ni)
            bfr[ni] = *(const bf16x8*)&Bs[(wn + ni * 16 + l16) * LDK + quad * 8];
#pragma unroll
        for (int mi = 0; mi < 4; ++mi)
#pragma unroll
            for (int ni = 0; ni < 4; ++ni)
                acc[mi][ni] = __builtin_amdgcn_mfma_f32_16x16x32_bf16(
                    af[mi], bfr[ni], acc[mi][ni], 0, 0, 0);
    }

    // C/D layout: col = lane&15, row = quad*4 + r
#pragma unroll
    for (int mi = 0; mi < 4; ++mi)
#pragma unroll
        for (int ni = 0; ni < 4; ++ni)
#pragma unroll
            for (int r = 0; r < 4; ++r) {
                int row = bm + wm + mi * 16 + quad * 4 + r;
                int col = bn + wn + ni * 16 + l16;
                if (row < M)
                    Cbf[(size_t)row * Nc + col] = f2bf(acc[mi][ni][r]);
            }

    // ---- attention-dot epilogue ----
    float asc[4], adc[4];
#pragma unroll
    for (int ni = 0; ni < 4; ++ni) {
        int col = bn + wn + ni * 16 + l16;
        bool valid = col < attN;
        asc[ni] = valid ? att_s[col] : 0.f;
        adc[ni] = valid ? att_d[col] : 0.f;
    }
    float vs[16], vd[16];
#pragma unroll
    for (int mi = 0; mi < 4; ++mi)
#pragma unroll
        for (int r = 0; r < 4; ++r) {
            float s = 0.f, dd = 0.f;
#pragma unroll
            for (int ni = 0; ni < 4; ++ni) {
                s += acc[mi][ni][r] * asc[ni];
                dd += acc[mi][ni][r] * adc[ni];
            }
            vs[mi * 4 + r] = s;
            vd[mi * 4 + r] = dd;
        }
    // butterfly all-reduce across l16: lane l16 ends holding row i = l16 (i = mi*4+r)
#pragma unroll
    for (int k = 0; k < 4; ++k) {
        const int o = 1 << k;
        const int b = (l16 >> k) & 1;
#pragma unroll
        for (int j = 0; j < (8 >> k); ++j) {
            float lo = vs[2 * j], hi = vs[2 * j + 1];
            float keep = b ? hi : lo, send = b ? lo : hi;
            vs[j] = keep + __shfl_xor(send, o);
            lo = vd[2 * j]; hi = vd[2 * j + 1];
            keep = b ? hi : lo; send = b ? lo : hi;
            vd[j] = keep + __shfl_xor(send, o);
        }
    }
    {
        int mi = l16 >> 2, r = l16 & 3;
        int row = bm + wm + mi * 16 + quad * 4 + r;
        int head = (bn + wn) >> 6;
        if (row < M) {
            a_src_o[(size_t)row * hstride + head] = vs[0];
            a_dst_o[(size_t)row * hstride + head] = vd[0];
        }
    }
}

// ---------------- layer 1 fused: half-wave-per-dst softmax (4 heads) + aggregation ------
// 2 dsts per wave (32 lanes each); deg <= 32 fast path (covers ~all of this graph).
// LATENCY-PIPELINED fast path:
//  * h1bf row gathers for batches 0/1 ISSUED right after the csr load (addresses depend
//    only on es0.y, broadcast via __shfl) - they fly under the a_src gather + softmax.
//  * FMA loop 2-stage software-pipelined (qa/qb banks, up to 8 x 1KiB wave-loads out).
//  * Weight A = p[edge j][head of RECEIVING lane]: source-lane-index x receiver-lane-
//    component cross-access -> CANNOT be one __shfl (round-4 bug: __shfl(phead, j)
//    returned p[edge j][head j>>3], head-mixed). Stage p as float4 in wave-private LDS
//    (same-wave DS ops in-order, no barrier - validated pattern) and read
//    aw[4*j + headc]. Edge INDEX stays __shfl (scalar - correct).
// Max subtraction kept (p <= 1: order-robust aggregation across CSR replay orders).
// General deg > 32 path (rare): LDS-staged multi-pass, unchanged.

#define L1_LOADQ(q, jb)                                                         \
    _Pragma("unroll")                                                           \
    for (int k = 0; k < 4; ++k) {                                               \
        int s_ = __shfl(esy, shbase + (jb) + k);                                \
        q[k] = *(const uint4*)&h1bf[(unsigned)s_ * 128u + 4u * li];             \
    }

#define L1_FMAQ(q, jb)                                                          \
    _Pragma("unroll")                                                           \
    for (int k = 0; k < 4; ++k) {                                               \
        float A_ = aw[4 * ((jb) + k) + headc];                                  \
        acc8(ac, A_, q[k]);                                                     \
    }

__global__ __launch_bounds__(256) void l1_fused_kernel(const int* __restrict__ off,
                                                       const int2* __restrict__ csr_es,
                                                       const float4* __restrict__ a_src4,
                                                       const float4* __restrict__ a_dst4,
                                                       const unsigned* __restrict__ h1bf,
                                                       const float* __restrict__ b1,
                                                       float4* __restrict__ alpha_out4,
                                                       unsigned* __restrict__ out1bf) {
    __shared__ int    s_w[4][2][32];
    __shared__ float4 p_w[4][2][32];
    int t = threadIdx.x;
    int w = t >> 6, lane = t & 63;
    int half = lane >> 5, li = lane & 31;
    int shbase = half << 5;
    int d = blockIdx.x * 8 + w * 2 + half;   // 50000 = 6250*8, always valid
    int beg = off[d], end = off[d + 1];
    int deg = end - beg;
    int nch = (deg + 31) >> 5;
    int cnt0 = min(deg, 32);
    bool act0 = li < cnt0;
    float4 ad4 = a_dst4[d];
    int headc = li >> 3;

    float ac[8] = {};
    float4 sum = make_float4(0.f, 0.f, 0.f, 0.f);
    float4 mx = make_float4(-INFINITY, -INFINITY, -INFINITY, -INFINITY);
    int2 es0 = make_int2(0, 0);
    float4 p0 = make_float4(0.f, 0.f, 0.f, 0.f);

    const float* aw = (const float*)&p_w[w][half][0];
    const int*   sw = &s_w[w][half][0];

    if (nch == 1) {
        // ---------- FAST PATH (deg <= 32) ----------
        float4 l0 = make_float4(-INFINITY, -INFINITY, -INFINITY, -INFINITY);
        float4 as4 = make_float4(0.f, 0.f, 0.f, 0.f);
        if (act0) {
            es0 = csr_es[beg + li];
            as4 = a_src4[es0.y];               // issued first (feeds softmax chain)
        }
        int esy = es0.y;                       // 0 on inactive lanes -> safe row 0
        const int B = (cnt0 + 3) >> 2;         // 4-edge batches, >= 1 (self-loop)

        // prefetch batches 0 and 1 NOW - they fly under the whole softmax phase
        uint4 qa[4], qb[4];
        L1_LOADQ(qa, 0);
        if (B > 1) { L1_LOADQ(qb, 4); }

        if (act0) {
            l0.x = leaky(as4.x + ad4.x);
            l0.y = leaky(as4.y + ad4.y);
            l0.z = leaky(as4.z + ad4.z);
            l0.w = leaky(as4.w + ad4.w);
        }
        // fixed 5-level max butterfly (inactive lanes hold -inf)
        mx = l0;
#pragma unroll
        for (int o = 1; o <= 16; o <<= 1) {
            mx.x = fmaxf(mx.x, __shfl_xor(mx.x, o));
            mx.y = fmaxf(mx.y, __shfl_xor(mx.y, o));
            mx.z = fmaxf(mx.z, __shfl_xor(mx.z, o));
            mx.w = fmaxf(mx.w, __shfl_xor(mx.w, o));
        }
        // p in [0,1]; inactive lanes: exp(-inf - finite) = 0
        p0.x = __expf(l0.x - mx.x);
        p0.y = __expf(l0.y - mx.y);
        p0.z = __expf(l0.z - mx.z);
        p0.w = __expf(l0.w - mx.w);
        p_w[w][half][li] = p0;                 // stage (inactive lanes store zeros)
        sum = p0;

        // ---- 2-stage pipelined aggregation ----
        int i = 0;
        for (; i + 2 <= B; i += 2) {
            L1_FMAQ(qa, i * 4);
            if (i + 2 < B) { L1_LOADQ(qa, (i + 2) * 4); }
            L1_FMAQ(qb, i * 4 + 4);
            if (i + 3 < B) { L1_LOADQ(qb, (i + 3) * 4); }
        }
        if (i < B) { L1_FMAQ(qa, i * 4); }
    } else {
        // ---------- GENERAL PATH pass A1: max (deg > 32; rare) ----------
        for (int cc = 0; cc < nch; ++cc) {
            int idx = beg + cc * 32 + li;
            if (idx < end) {
                int2 es = csr_es[idx];
                float4 as4 = a_src4[es.y];
                mx.x = fmaxf(mx.x, leaky(as4.x + ad4.x));
                mx.y = fmaxf(mx.y, leaky(as4.y + ad4.y));
                mx.z = fmaxf(mx.z, leaky(as4.z + ad4.z));
                mx.w = fmaxf(mx.w, leaky(as4.w + ad4.w));
            }
        }
#pragma unroll
        for (int o = 1; o <= 16; o <<= 1) {
            mx.x = fmaxf(mx.x, __shfl_xor(mx.x, o));
            mx.y = fmaxf(mx.y, __shfl_xor(mx.y, o));
            mx.z = fmaxf(mx.z, __shfl_xor(mx.z, o));
            mx.w = fmaxf(mx.w, __shfl_xor(mx.w, o));
        }
        // ---------- pass A2: sum ----------
        for (int cc = 0; cc < nch; ++cc) {
            int idx = beg + cc * 32 + li;
            if (idx < end) {
                int2 es = csr_es[idx];
                float4 as4 = a_src4[es.y];
                sum.x += __expf(leaky(as4.x + ad4.x) - mx.x);
                sum.y += __expf(leaky(as4.y + ad4.y) - mx.y);
                sum.z += __expf(leaky(as4.z + ad4.z) - mx.z);
                sum.w += __expf(leaky(as4.w + ad4.w) - mx.w);
            }
        }
    }

    // fixed 5-level butterfly all-reduce within the 32-lane half
#pragma unroll
    for (int o = 1; o <= 16; o <<= 1) {
        sum.x += __shfl_xor(sum.x, o);
        sum.y += __shfl_xor(sum.y, o);
        sum.z += __shfl_xor(sum.z, o);
        sum.w += __shfl_xor(sum.w, o);
    }
    float4 inv;
    inv.x = 1.f / (sum.x + EPS_A); inv.y = 1.f / (sum.y + EPS_A);
    inv.z = 1.f / (sum.z + EPS_A); inv.w = 1.f / (sum.w + EPS_A);
    float invh = (headc == 0) ? inv.x : (headc == 1) ? inv.y
               : (headc == 2) ? inv.z : inv.w;

    if (nch == 1) {
        if (act0) {
            float4 al0;
            al0.x = p0.x * inv.x; al0.y = p0.y * inv.y;
            al0.z = p0.z * inv.z; al0.w = p0.w * inv.w;
            alpha_out4[es0.x] = al0;
        }
    } else {
        // ---------- GENERAL PATH pass B: stage + aggregate + alpha ----------
        for (int cc = 0; cc < nch; ++cc) {
            int idx = beg + cc * 32 + li;
            int cnt = min(32, deg - cc * 32);
            if (idx < end) {
                int2 es = csr_es[idx];
                float4 as4 = a_src4[es.y];
                float4 p;
                p.x = __expf(leaky(as4.x + ad4.x) - mx.x);
                p.y = __expf(leaky(as4.y + ad4.y) - mx.y);
                p.z = __expf(leaky(as4.z + ad4.z) - mx.z);
                p.w = __expf(leaky(as4.w + ad4.w) - mx.w);
                float4 al;
                al.x = p.x * inv.x; al.y = p.y * inv.y;
                al.z = p.z * inv.z; al.w = p.w * inv.w;
                alpha_out4[es.x] = al;
                s_w[w][half][li] = es.y;
                p_w[w][half][li] = p;       // UNNORMALIZED
            }
            for (int j = 0; j < cnt; ++j) {
                int s = sw[j];
                float A = aw[4 * j + headc];
                uint4 q = *(const uint4*)&h1bf[(unsigned)s * 128u + 4u * li];
                acc8(ac, A, q);
            }
        }
    }

#pragma unroll
    for (int c = 0; c < 8; ++c) ac[c] *= invh;

    // ---- epilogue: bias + ELU -> bf16 packed (each half writes its own dst) ----
    float4 bb0 = *(const float4*)&b1[8 * li];
    float4 bb1 = *(const float4*)&b1[8 * li + 4];
    float v0 = ac[0] + bb0.x, v1 = ac[1] + bb0.y;
    float v2 = ac[2] + bb0.z, v3 = ac[3] + bb0.w;
    float v4 = ac[4] + bb1.x, v5 = ac[5] + bb1.y;
    float v6 = ac[6] + bb1.z, v7 = ac[7] + bb1.w;
    v0 = v0 > 0.f ? v0 : __expf(v0) - 1.f;
    v1 = v1 > 0.f ? v1 : __expf(v1) - 1.f;
    v2 = v2 > 0.f ? v2 : __expf(v2) - 1.f;
    v3 = v3 > 0.f ? v3 : __expf(v3) - 1.f;
    v4 = v4 > 0.f ? v4 : __expf(v4) - 1.f;
    v5 = v5 > 0.f ? v5 : __expf(v5) - 1.f;
    v6 = v6 > 0.f ? v6 : __expf(v6) - 1.f;
    v7 = v7 > 0.f ? v7 : __expf(v7) - 1.f;
    uint4 qo;
    qo.x = ((unsigned)f2bf(v1) << 16) | (unsigned)f2bf(v0);
    qo.y = ((unsigned)f2bf(v3) << 16) | (unsigned)f2bf(v2);
    qo.z = ((unsigned)f2bf(v5) << 16) | (unsigned)f2bf(v4);
    qo.w = ((unsigned)f2bf(v7) << 16) | (unsigned)f2bf(v6);
    *(uint4*)&out1bf[(size_t)d * 128 + 4 * li] = qo;
}

// ---------------- layer 2 fused: half-wave-per-dst + log_softmax ----------------
// Same latency-pipelining as l1. Single head -> p is SCALAR per edge, so the
// __shfl(p0, j) broadcast IS correct here (no per-head component selection).
// Max subtraction kept. General deg > 32 path: LDS-staged, unchanged.

#define L2_LOADQ(q, jb)                                                         \
    _Pragma("unroll")                                                           \
    for (int k = 0; k < 4; ++k) {                                               \
        int s_ = __shfl(s0, shbase + (jb) + k);                                 \
        q[k] = h2bf[(unsigned)s_ * 32u + li];                                   \
    }

#define L2_FMAQ(q, jb)                                                          \
    _Pragma("unroll")                                                           \
    for (int k = 0; k < 4; ++k) {                                               \
        float A_ = __shfl(p0, shbase + (jb) + k);                               \
        acc0 += A_ * bf_lo(q[k]);                                               \
        acc1 += A_ * bf_hi(q[k]);                                               \
    }

__global__ __launch_bounds__(256) void l2_fused_kernel(const int* __restrict__ off,
                                                       const int2* __restrict__ csr_es,
                                                       const float* __restrict__ a_src,
                                                       const float* __restrict__ a_dst,
                                                       const unsigned* __restrict__ h2bf,
                                                       const float* __restrict__ b2,
                                                       float* __restrict__ out) {
    __shared__ uint2 sp_w[4][2][32];
    int t = threadIdx.x;
    int w = t >> 6, lane = t & 63;
    int half = lane >> 5, li = lane & 31;
    int shbase = half << 5;
    int d = blockIdx.x * 8 + w * 2 + half;
    int beg = off[d], end = off[d + 1];
    int deg = end - beg;
    float ad = a_dst[d];
    int nch = (deg + 31) >> 5;
    int cnt0 = min(deg, 32);
    bool act0 = li < cnt0;

    float sum = 0.f, acc0 = 0.f, acc1 = 0.f;
    float p0 = 0.f;

    if (nch == 1) {
        // ---------- FAST PATH (deg <= 32) ----------
        float el0 = -INFINITY; int s0 = 0;
        if (act0) {
            int2 es = csr_es[beg + li];
            s0 = es.y;
            el0 = leaky(a_src[s0] + ad);
        }
        const int B = (cnt0 + 3) >> 2;
        unsigned qa[4], qb[4];
        L2_LOADQ(qa, 0);
        if (B > 1) { L2_LOADQ(qb, 4); }

        float mx = el0;
#pragma unroll
        for (int o = 1; o <= 16; o <<= 1) mx = fmaxf(mx, __shfl_xor(mx, o));
        p0 = __expf(el0 - mx);             // inactive: exp(-inf) = 0
        sum = p0;

        int i = 0;
        for (; i + 2 <= B; i += 2) {
            L2_FMAQ(qa, i * 4);
            if (i + 2 < B) { L2_LOADQ(qa, (i + 2) * 4); }
            L2_FMAQ(qb, i * 4 + 4);
            if (i + 3 < B) { L2_LOADQ(qb, (i + 3) * 4); }
        }
        if (i < B) { L2_FMAQ(qa, i * 4); }
    } else {
        // ---------- GENERAL PATH (deg > 32; rare) ----------
        float mx = -INFINITY;
        for (int cc = 0; cc < nch; ++cc) {
            int idx = beg + cc * 32 + li;
            if (idx < end) {
                int2 es = csr_es[idx];
                mx = fmaxf(mx, leaky(a_src[es.y] + ad));
            }
        }
#pragma unroll
        for (int o = 1; o <= 16; o <<= 1) mx = fmaxf(mx, __shfl_xor(mx, o));
        // merged stage + aggregate with unnormalized p
        for (int cc = 0; cc < nch; ++cc) {
            int idx = beg + cc * 32 + li;
            int cnt = min(32, deg - cc * 32);
            if (idx < end) {
                int2 es = csr_es[idx];
                float el = leaky(a_src[es.y] + ad);
                float p = __expf(el - mx);
                sum += p;
                sp_w[w][half][li] = make_uint2((unsigned)es.y, __float_as_uint(p));
            }
            for (int j = 0; j < cnt; ++j) {
                uint2 e0 = sp_w[w][half][j];
                float A0 = __uint_as_float(e0.y);
                unsigned q = h2bf[e0.x * 32u + li];
                acc0 += A0 * bf_lo(q);
                acc1 += A0 * bf_hi(q);
            }
        }
    }

    // fixed 5-level butterfly all-reduce within half
#pragma unroll
    for (int o = 1; o <= 16; o <<= 1) sum += __shfl_xor(sum, o);
    float inv = 1.f / (sum + EPS_A);
    acc0 *= inv;
    acc1 *= inv;

    bool act = li < 20;
    float v0 = act ? acc0 + b2[2 * li]     : -INFINITY;
    float v1 = act ? acc1 + b2[2 * li + 1] : -INFINITY;
    float mmx = fmaxf(v0, v1);
#pragma unroll
    for (int o = 16; o; o >>= 1) mmx = fmaxf(mmx, __shfl_xor(mmx, o));
    float ex = act ? __expf(v0 - mmx) + __expf(v1 - mmx) : 0.f;
#pragma unroll
    for (int o = 16; o; o >>= 1) ex += __shfl_xor(ex, o);
    float ls = __logf(ex);
    if (act)
        *(float2*)&out[(size_t)d * C2 + 2 * li] = make_float2(v0 - mmx - ls, v1 - mmx - ls);
}

// ---------------- launcher ----------------

extern "C" void kernel_launch(void* const* d_in, const int* in_sizes, int n_in,
                              void* d_out, int out_size, void* d_ws, size_t ws_size,
                              hipStream_t stream) {
    const float* x   = (const float*)d_in[0];
    const int*   ei  = (const int*)d_in[1];
    const float* W1  = (const float*)d_in[2];
    const float* as1 = (const float*)d_in[3];
    const float* ad1 = (const float*)d_in[4];
    const float* b1  = (const float*)d_in[5];
    const float* W2  = (const float*)d_in[6];
    const float* as2 = (const float*)d_in[7];
    const float* ad2 = (const float*)d_in[8];
    const float* b2  = (const float*)d_in[9];

    float* out   = (float*)d_out;
    float* alpha = out + (size_t)N_NODES * C2;    // [ET, 4] final output region

    unsigned* u32    = (unsigned*)d_ws;
    unsigned* h1bf   = u32;                       // 6,400,000 u32 (50000x256 bf16)
    unsigned* xbf    = h1bf + 6400000;            // 6,400,000 u32; ALIASES out1bf
    unsigned* h2bf   = xbf + 6400000;             // 1,600,000 u32 (50000x64 bf16)
    unsigned* w1t    = h2bf + 1600000;            // 32,768 u32
    unsigned* w2t    = w1t + 32768;               // 8,192 u32
    float* a_src1    = (float*)(w2t + 8192);      // 200,000 f (16B-aligned)
    float* a_dst1    = a_src1 + 200000;           // 200,000 f
    float* a_src2    = a_dst1 + 200000;           // 50,000 f
    float* a_dst2    = a_src2 + 50000;            // 50,000 f
    int*   deg       = (int*)(a_dst2 + 50000);    // 50,000 i
    int*   offs      = deg + 50000;               // 50,001 i
    int*   cursor    = offs + 50001;              // 50,000 i
    int*   bsum      = cursor + 50000;            // 256 i + 1 pad
    int2*  csr_es    = (int2*)(bsum + 257);       // 850,000 int2 (8B-aligned)
    unsigned* out1bf = xbf;                       // alias: xbf dead after GEMM1

    const int TB = 256;
    const int EB = (ET + TB - 1) / TB;

    // --- converts + deg zeroing (merged) ---
    convert_all_kernel<<<(CV_TOT + TB - 1) / TB, TB, 0, stream>>>(
        x, W1, W2, (ushort4*)xbf, (unsigned short*)w1t, (unsigned short*)w2t, deg);

    // --- CSR build ---
    hist_kernel<<<EB, TB, 0, stream>>>(ei, deg);
    scan_block_kernel<<<NSCAN_B, TB, 0, stream>>>(deg, offs, bsum);
    scan_top_kernel<<<1, TB, 0, stream>>>(bsum);
    scan_add_kernel<<<NSCAN_B, TB, 0, stream>>>(offs, cursor, bsum);
    scatter_kernel<<<EB, TB, 0, stream>>>(ei, cursor, csr_es);

    // --- layer 1 ---
    gemm_mfma_kernel<128, 128, 2, 2><<<dim3((N_NODES + 127) / 128, 2), TB, 0, stream>>>(
        (const unsigned short*)xbf, (const unsigned short*)w1t, (unsigned short*)h1bf,
        as1, ad1, a_src1, a_dst1, N_NODES, HC1, 256, H1);
    l1_fused_kernel<<<N_NODES / 8, TB, 0, stream>>>(offs, csr_es,
                                                    (const float4*)a_src1,
                                                    (const float4*)a_dst1,
                                                    h1bf, b1, (float4*)alpha, out1bf);

    // --- layer 2 ---
    gemm_mfma_kernel<256, 64, 4, 1><<<dim3((N_NODES + 255) / 256, 1), TB, 0, stream>>>(
        (const unsigned short*)out1bf, (const unsigned short*)w2t, (unsigned short*)h2bf,
        as2, ad2, a_src2, a_dst2, N_NODES, C2P, C2, 1);
    l2_fused_kernel<<<N_NODES / 8, TB, 0, stream>>>(offs, csr_es, a_src2, a_dst2,
                                                    h2bf, b2, out);
}

// Round 6
// 356.428 us; speedup vs baseline: 1.0069x; 1.0069x over previous
//
#include <hip/hip_runtime.h>
#include <math.h>

#define N_NODES 50000
#define HC1 256      // 4 heads * 64 ch
#define H1 4
#define C2 40
#define C2P 64       // padded
#define E0 800000
#define ET 850000
#define NEG_SLOPE 0.2f
#define EPS_A 1e-16f

typedef __bf16 bf16x8 __attribute__((ext_vector_type(8)));
typedef float f32x4 __attribute__((ext_vector_type(4)));
typedef unsigned short u16x8 __attribute__((ext_vector_type(8)));

// ---------------- bf16 helpers (RNE) ----------------

__device__ inline unsigned short f2bf(float f) {
    unsigned u = __float_as_uint(f);
    return (unsigned short)((u + 0x7FFFu + ((u >> 16) & 1u)) >> 16);
}
__device__ inline float bf_lo(unsigned q) { return __uint_as_float(q << 16); }
__device__ inline float bf_hi(unsigned q) { return __uint_as_float(q & 0xFFFF0000u); }

// ---------------- utility ----------------

__device__ inline int edge_src(const int* __restrict__ ei, int e) {
    return (e < E0) ? ei[e] : (e - E0);
}
__device__ inline int edge_dst(const int* __restrict__ ei, int e) {
    return (e < E0) ? ei[E0 + e] : (e - E0);
}

// 8-channel bf16-pair FMA accumulate
__device__ inline void acc8(float ac[8], float A, uint4 q) {
    ac[0] += A * bf_lo(q.x); ac[1] += A * bf_hi(q.x);
    ac[2] += A * bf_lo(q.y); ac[3] += A * bf_hi(q.y);
    ac[4] += A * bf_lo(q.z); ac[5] += A * bf_hi(q.z);
    ac[6] += A * bf_lo(q.w); ac[7] += A * bf_hi(q.w);
}

__device__ inline float leaky(float v) { return v > 0.f ? v : NEG_SLOPE * v; }

// ------- merged prep: x->bf16, W1^T->bf16, W2^T(padded)->bf16, + DEGREE HISTOGRAM -----
// deg[] is zeroed by hipMemsetAsync BEFORE this kernel, so the atomic histogram can run
// in the same dispatch as the converts: 850k random atomics hide under 77MB streaming.

#define CV_X 3200000          // float4 groups of x
#define CV_W1 65536
#define CV_W2 16384
#define CV_TOT (CV_X + CV_W1 + CV_W2 + ET)

__global__ void convert_all_kernel(const float* __restrict__ x,
                                   const float* __restrict__ W1,
                                   const float* __restrict__ W2,
                                   const int* __restrict__ ei,
                                   ushort4* __restrict__ xbf,
                                   unsigned short* __restrict__ w1t,
                                   unsigned short* __restrict__ w2t,
                                   int* __restrict__ deg) {
    int tid = blockIdx.x * blockDim.x + threadIdx.x;
    if (tid < CV_X) {
        float4 v = ((const float4*)x)[tid];
        ushort4 w;
        w.x = f2bf(v.x); w.y = f2bf(v.y); w.z = f2bf(v.z); w.w = f2bf(v.w);
        xbf[tid] = w;
    } else if (tid < CV_X + CV_W1) {
        int i = tid - CV_X;
        int n = i >> 8, k = i & 255;
        w1t[i] = f2bf(W1[k * 256 + n]);
    } else if (tid < CV_X + CV_W1 + CV_W2) {
        int i = tid - CV_X - CV_W1;
        int n = i >> 8, k = i & 255;
        w2t[i] = (n < C2) ? f2bf(W2[k * C2 + n]) : (unsigned short)0;
    } else if (tid < CV_TOT) {
        int e = tid - CV_X - CV_W1 - CV_W2;
        atomicAdd(&deg[edge_dst(ei, e)], 1);
    }
}

// ---------------- CSR build ----------------

__global__ __launch_bounds__(256) void scan_block_kernel(const int* __restrict__ deg,
                                                         int* __restrict__ excl,
                                                         int* __restrict__ bsum) {
    __shared__ int tmp[256];
    int t = threadIdx.x;
    int i = blockIdx.x * 256 + t;
    int v = (i < N_NODES) ? deg[i] : 0;
    tmp[t] = v;
    __syncthreads();
#pragma unroll
    for (int o = 1; o < 256; o <<= 1) {
        int x = (t >= o) ? tmp[t - o] : 0;
        __syncthreads();
        tmp[t] += x;
        __syncthreads();
    }
    if (i < N_NODES) excl[i] = tmp[t] - v;
    if (t == 255) bsum[blockIdx.x] = tmp[255];
}

#define NSCAN_B 196   // ceil(50000/256)

__global__ __launch_bounds__(256) void scan_top_kernel(int* __restrict__ bsum) {
    __shared__ int tmp[256];
    int t = threadIdx.x;
    int v = (t < NSCAN_B) ? bsum[t] : 0;
    tmp[t] = v;
    __syncthreads();
#pragma unroll
    for (int o = 1; o < 256; o <<= 1) {
        int x = (t >= o) ? tmp[t - o] : 0;
        __syncthreads();
        tmp[t] += x;
        __syncthreads();
    }
    if (t < NSCAN_B) bsum[t] = tmp[t] - v;   // exclusive
}

__global__ __launch_bounds__(256) void scan_add_kernel(int* __restrict__ offsets,
                                                       int* __restrict__ cursor,
                                                       const int* __restrict__ bsum) {
    int i = blockIdx.x * 256 + threadIdx.x;
    if (i < N_NODES) {
        int v = offsets[i] + bsum[blockIdx.x];
        offsets[i] = v;
        cursor[i] = v;
    }
    if (i == 0) offsets[N_NODES] = ET;
}

// writes (edge id, src id) as one int2 in CSR order
__global__ void scatter_kernel(const int* __restrict__ ei, int* __restrict__ cursor,
                               int2* __restrict__ csr_es) {
    int e = blockIdx.x * blockDim.x + threadIdx.x;
    if (e >= ET) return;
    int d = edge_dst(ei, e);
    int pos = atomicAdd(&cursor[d], 1);
    csr_es[pos] = make_int2(e, edge_src(ei, e));
}

// ---------------- MFMA GEMM + attention-dot epilogue ----------------
// Cbf[M,Nc] = bf16( Abf[M,256] * Bt[Nc,256]^T ); K = 256.
// DOUBLE-BUFFERED LDS: one barrier per 32-wide K-step (was two); staging of step k+1
// overlaps MFMA of step k. K=256 is only 8 steps, so barrier drain was a large cost.
// Epilogue: a_src_o[row*hstride+head] = sum_col acc*att_s[col] (head = wave col-base/64).
// Wave tile 64x64 (4x4 of 16x16x32 mfma). LDS stride 40 bf16 -> 2-way aliasing (free).

#define GEMM_STAGE(k0v, bufv)                                                     \
    _Pragma("unroll")                                                             \
    for (int i = 0; i < TBM / 64; ++i) {                                          \
        int idx = t + i * 256;                                                    \
        int row = idx >> 2, seg = idx & 3;                                        \
        u16x8 v = {};                                                             \
        if (bm + row < M)                                                         \
            v = *(const u16x8*)(Abf + (size_t)(bm + row) * 256 + (k0v) + seg * 8);\
        *(u16x8*)&As[bufv][row * LDK + seg * 8] = v;                              \
    }                                                                             \
    _Pragma("unroll")                                                             \
    for (int i = 0; i < TBN / 64; ++i) {                                          \
        int idx = t + i * 256;                                                    \
        int row = idx >> 2, seg = idx & 3;                                        \
        u16x8 v = *(const u16x8*)(Bt + (size_t)(bn + row) * 256 + (k0v) + seg * 8);\
        *(u16x8*)&Bs[bufv][row * LDK + seg * 8] = v;                              \
    }

template <int TBM, int TBN, int WROWS, int WCOLS>
__global__ __launch_bounds__(256) void gemm_mfma_kernel(const unsigned short* __restrict__ Abf,
                                                        const unsigned short* __restrict__ Bt,
                                                        unsigned short* __restrict__ Cbf,
                                                        const float* __restrict__ att_s,
                                                        const float* __restrict__ att_d,
                                                        float* __restrict__ a_src_o,
                                                        float* __restrict__ a_dst_o,
                                                        int M, int Nc, int attN, int hstride) {
    static_assert(TBM == WROWS * 64 && TBN == WCOLS * 64, "tile");
    constexpr int LDK = 40;
    __shared__ alignas(16) unsigned short As[2][TBM * LDK];
    __shared__ alignas(16) unsigned short Bs[2][TBN * LDK];
    const int t = threadIdx.x;
    const int lane = t & 63;
    const int w = t >> 6;
    const int quad = lane >> 4;
    const int l16 = lane & 15;
    const int wm = (w / WCOLS) * 64;
    const int wn = (w % WCOLS) * 64;
    const int bm = blockIdx.x * TBM;
    const int bn = blockIdx.y * TBN;

    f32x4 acc[4][4] = {};

    GEMM_STAGE(0, 0);
    int cur = 0;
    for (int k0 = 0; k0 < 256; k0 += 32) {
        __syncthreads();   // staging of buf[cur] visible; prior reads of buf[cur^1] done
        if (k0 + 32 < 256) { GEMM_STAGE(k0 + 32, cur ^ 1); }

        bf16x8 af[4], bfr[4];
#pragma unroll
        for (int mi = 0; mi < 4; ++mi)
            af[mi] = *(const bf16x8*)&As[cur][(wm + mi * 16 + l16) * LDK + quad * 8];
#pragma unroll
        for (int ni = 0; ni < 4; ++ni)
            bfr[ni] = *(const bf16x8*)&Bs[cur][(wn + ni * 16 + l16) * LDK + quad * 8];
#pragma unroll
        for (int mi = 0; mi < 4; ++mi)
#pragma unroll
            for (int ni = 0; ni < 4; ++ni)
                acc[mi][ni] = __builtin_amdgcn_mfma_f32_16x16x32_bf16(
                    af[mi], bfr[ni], acc[mi][ni], 0, 0, 0);
        cur ^= 1;
    }

    // C/D layout: col = lane&15, row = quad*4 + r
#pragma unroll
    for (int mi = 0; mi < 4; ++mi)
#pragma unroll
        for (int ni = 0; ni < 4; ++ni)
#pragma unroll
            for (int r = 0; r < 4; ++r) {
                int row = bm + wm + mi * 16 + quad * 4 + r;
                int col = bn + wn + ni * 16 + l16;
                if (row < M)
                    Cbf[(size_t)row * Nc + col] = f2bf(acc[mi][ni][r]);
            }

    // ---- attention-dot epilogue ----
    float asc[4], adc[4];
#pragma unroll
    for (int ni = 0; ni < 4; ++ni) {
        int col = bn + wn + ni * 16 + l16;
        bool valid = col < attN;
        asc[ni] = valid ? att_s[col] : 0.f;
        adc[ni] = valid ? att_d[col] : 0.f;
    }
    float vs[16], vd[16];
#pragma unroll
    for (int mi = 0; mi < 4; ++mi)
#pragma unroll
        for (int r = 0; r < 4; ++r) {
            float s = 0.f, dd = 0.f;
#pragma unroll
            for (int ni = 0; ni < 4; ++ni) {
                s += acc[mi][ni][r] * asc[ni];
                dd += acc[mi][ni][r] * adc[ni];
            }
            vs[mi * 4 + r] = s;
            vd[mi * 4 + r] = dd;
        }
    // butterfly all-reduce across l16: lane l16 ends holding row i = l16 (i = mi*4+r)
#pragma unroll
    for (int k = 0; k < 4; ++k) {
        const int o = 1 << k;
        const int b = (l16 >> k) & 1;
#pragma unroll
        for (int j = 0; j < (8 >> k); ++j) {
            float lo = vs[2 * j], hi = vs[2 * j + 1];
            float keep = b ? hi : lo, send = b ? lo : hi;
            vs[j] = keep + __shfl_xor(send, o);
            lo = vd[2 * j]; hi = vd[2 * j + 1];
            keep = b ? hi : lo; send = b ? lo : hi;
            vd[j] = keep + __shfl_xor(send, o);
        }
    }
    {
        int mi = l16 >> 2, r = l16 & 3;
        int row = bm + wm + mi * 16 + quad * 4 + r;
        int head = (bn + wn) >> 6;
        if (row < M) {
            a_src_o[(size_t)row * hstride + head] = vs[0];
            a_dst_o[(size_t)row * hstride + head] = vd[0];
        }
    }
}

// ---------------- layer 1 fused: half-wave-per-dst softmax (4 heads) + aggregation ------
// AT MEMORY-MIX ROOFLINE (r5 analysis: ~495MB delivered in ~80us = 6.2 TB/s ~ 6.3 ceiling;
// three structurally different variants all land 78-85us with FETCH pinned at 216MB).
// Kept exactly as the round-5 verified version.
// 2 dsts per wave (32 lanes each); deg <= 32 fast path; batches 0/1 prefetched under the
// softmax; 2-stage pipelined FMA loop; p staged per-head in wave-private LDS (same-wave
// DS in-order, no barrier); edge index broadcast via __shfl. Max subtraction kept.

#define L1_LOADQ(q, jb)                                                         \
    _Pragma("unroll")                                                           \
    for (int k = 0; k < 4; ++k) {                                               \
        int s_ = __shfl(esy, shbase + (jb) + k);                                \
        q[k] = *(const uint4*)&h1bf[(unsigned)s_ * 128u + 4u * li];             \
    }

#define L1_FMAQ(q, jb)                                                          \
    _Pragma("unroll")                                                           \
    for (int k = 0; k < 4; ++k) {                                               \
        float A_ = aw[4 * ((jb) + k) + headc];                                  \
        acc8(ac, A_, q[k]);                                                     \
    }

__global__ __launch_bounds__(256) void l1_fused_kernel(const int* __restrict__ off,
                                                       const int2* __restrict__ csr_es,
                                                       const float4* __restrict__ a_src4,
                                                       const float4* __restrict__ a_dst4,
                                                       const unsigned* __restrict__ h1bf,
                                                       const float* __restrict__ b1,
                                                       float4* __restrict__ alpha_out4,
                                                       unsigned* __restrict__ out1bf) {
    __shared__ int    s_w[4][2][32];
    __shared__ float4 p_w[4][2][32];
    int t = threadIdx.x;
    int w = t >> 6, lane = t & 63;
    int half = lane >> 5, li = lane & 31;
    int shbase = half << 5;
    int d = blockIdx.x * 8 + w * 2 + half;   // 50000 = 6250*8, always valid
    int beg = off[d], end = off[d + 1];
    int deg = end - beg;
    int nch = (deg + 31) >> 5;
    int cnt0 = min(deg, 32);
    bool act0 = li < cnt0;
    float4 ad4 = a_dst4[d];
    int headc = li >> 3;

    float ac[8] = {};
    float4 sum = make_float4(0.f, 0.f, 0.f, 0.f);
    float4 mx = make_float4(-INFINITY, -INFINITY, -INFINITY, -INFINITY);
    int2 es0 = make_int2(0, 0);
    float4 p0 = make_float4(0.f, 0.f, 0.f, 0.f);

    const float* aw = (const float*)&p_w[w][half][0];
    const int*   sw = &s_w[w][half][0];

    if (nch == 1) {
        // ---------- FAST PATH (deg <= 32) ----------
        float4 l0 = make_float4(-INFINITY, -INFINITY, -INFINITY, -INFINITY);
        float4 as4 = make_float4(0.f, 0.f, 0.f, 0.f);
        if (act0) {
            es0 = csr_es[beg + li];
            as4 = a_src4[es0.y];               // issued first (feeds softmax chain)
        }
        int esy = es0.y;                       // 0 on inactive lanes -> safe row 0
        const int B = (cnt0 + 3) >> 2;         // 4-edge batches, >= 1 (self-loop)

        // prefetch batches 0 and 1 NOW - they fly under the whole softmax phase
        uint4 qa[4], qb[4];
        L1_LOADQ(qa, 0);
        if (B > 1) { L1_LOADQ(qb, 4); }

        if (act0) {
            l0.x = leaky(as4.x + ad4.x);
            l0.y = leaky(as4.y + ad4.y);
            l0.z = leaky(as4.z + ad4.z);
            l0.w = leaky(as4.w + ad4.w);
        }
        // fixed 5-level max butterfly (inactive lanes hold -inf)
        mx = l0;
#pragma unroll
        for (int o = 1; o <= 16; o <<= 1) {
            mx.x = fmaxf(mx.x, __shfl_xor(mx.x, o));
            mx.y = fmaxf(mx.y, __shfl_xor(mx.y, o));
            mx.z = fmaxf(mx.z, __shfl_xor(mx.z, o));
            mx.w = fmaxf(mx.w, __shfl_xor(mx.w, o));
        }
        // p in [0,1]; inactive lanes: exp(-inf - finite) = 0
        p0.x = __expf(l0.x - mx.x);
        p0.y = __expf(l0.y - mx.y);
        p0.z = __expf(l0.z - mx.z);
        p0.w = __expf(l0.w - mx.w);
        p_w[w][half][li] = p0;                 // stage (inactive lanes store zeros)
        sum = p0;

        // ---- 2-stage pipelined aggregation ----
        int i = 0;
        for (; i + 2 <= B; i += 2) {
            L1_FMAQ(qa, i * 4);
            if (i + 2 < B) { L1_LOADQ(qa, (i + 2) * 4); }
            L1_FMAQ(qb, i * 4 + 4);
            if (i + 3 < B) { L1_LOADQ(qb, (i + 3) * 4); }
        }
        if (i < B) { L1_FMAQ(qa, i * 4); }
    } else {
        // ---------- GENERAL PATH pass A1: max (deg > 32; rare) ----------
        for (int cc = 0; cc < nch; ++cc) {
            int idx = beg + cc * 32 + li;
            if (idx < end) {
                int2 es = csr_es[idx];
                float4 as4 = a_src4[es.y];
                mx.x = fmaxf(mx.x, leaky(as4.x + ad4.x));
                mx.y = fmaxf(mx.y, leaky(as4.y + ad4.y));
                mx.z = fmaxf(mx.z, leaky(as4.z + ad4.z));
                mx.w = fmaxf(mx.w, leaky(as4.w + ad4.w));
            }
        }
#pragma unroll
        for (int o = 1; o <= 16; o <<= 1) {
            mx.x = fmaxf(mx.x, __shfl_xor(mx.x, o));
            mx.y = fmaxf(mx.y, __shfl_xor(mx.y, o));
            mx.z = fmaxf(mx.z, __shfl_xor(mx.z, o));
            mx.w = fmaxf(mx.w, __shfl_xor(mx.w, o));
        }
        // ---------- pass A2: sum ----------
        for (int cc = 0; cc < nch; ++cc) {
            int idx = beg + cc * 32 + li;
            if (idx < end) {
                int2 es = csr_es[idx];
                float4 as4 = a_src4[es.y];
                sum.x += __expf(leaky(as4.x + ad4.x) - mx.x);
                sum.y += __expf(leaky(as4.y + ad4.y) - mx.y);
                sum.z += __expf(leaky(as4.z + ad4.z) - mx.z);
                sum.w += __expf(leaky(as4.w + ad4.w) - mx.w);
            }
        }
    }

    // fixed 5-level butterfly all-reduce within the 32-lane half
#pragma unroll
    for (int o = 1; o <= 16; o <<= 1) {
        sum.x += __shfl_xor(sum.x, o);
        sum.y += __shfl_xor(sum.y, o);
        sum.z += __shfl_xor(sum.z, o);
        sum.w += __shfl_xor(sum.w, o);
    }
    float4 inv;
    inv.x = 1.f / (sum.x + EPS_A); inv.y = 1.f / (sum.y + EPS_A);
    inv.z = 1.f / (sum.z + EPS_A); inv.w = 1.f / (sum.w + EPS_A);
    float invh = (headc == 0) ? inv.x : (headc == 1) ? inv.y
               : (headc == 2) ? inv.z : inv.w;

    if (nch == 1) {
        if (act0) {
            float4 al0;
            al0.x = p0.x * inv.x; al0.y = p0.y * inv.y;
            al0.z = p0.z * inv.z; al0.w = p0.w * inv.w;
            alpha_out4[es0.x] = al0;
        }
    } else {
        // ---------- GENERAL PATH pass B: stage + aggregate + alpha ----------
        for (int cc = 0; cc < nch; ++cc) {
            int idx = beg + cc * 32 + li;
            int cnt = min(32, deg - cc * 32);
            if (idx < end) {
                int2 es = csr_es[idx];
                float4 as4 = a_src4[es.y];
                float4 p;
                p.x = __expf(leaky(as4.x + ad4.x) - mx.x);
                p.y = __expf(leaky(as4.y + ad4.y) - mx.y);
                p.z = __expf(leaky(as4.z + ad4.z) - mx.z);
                p.w = __expf(leaky(as4.w + ad4.w) - mx.w);
                float4 al;
                al.x = p.x * inv.x; al.y = p.y * inv.y;
                al.z = p.z * inv.z; al.w = p.w * inv.w;
                alpha_out4[es.x] = al;
                s_w[w][half][li] = es.y;
                p_w[w][half][li] = p;       // UNNORMALIZED
            }
            for (int j = 0; j < cnt; ++j) {
                int s = sw[j];
                float A = aw[4 * j + headc];
                uint4 q = *(const uint4*)&h1bf[(unsigned)s * 128u + 4u * li];
                acc8(ac, A, q);
            }
        }
    }

#pragma unroll
    for (int c = 0; c < 8; ++c) ac[c] *= invh;

    // ---- epilogue: bias + ELU -> bf16 packed (each half writes its own dst) ----
    float4 bb0 = *(const float4*)&b1[8 * li];
    float4 bb1 = *(const float4*)&b1[8 * li + 4];
    float v0 = ac[0] + bb0.x, v1 = ac[1] + bb0.y;
    float v2 = ac[2] + bb0.z, v3 = ac[3] + bb0.w;
    float v4 = ac[4] + bb1.x, v5 = ac[5] + bb1.y;
    float v6 = ac[6] + bb1.z, v7 = ac[7] + bb1.w;
    v0 = v0 > 0.f ? v0 : __expf(v0) - 1.f;
    v1 = v1 > 0.f ? v1 : __expf(v1) - 1.f;
    v2 = v2 > 0.f ? v2 : __expf(v2) - 1.f;
    v3 = v3 > 0.f ? v3 : __expf(v3) - 1.f;
    v4 = v4 > 0.f ? v4 : __expf(v4) - 1.f;
    v5 = v5 > 0.f ? v5 : __expf(v5) - 1.f;
    v6 = v6 > 0.f ? v6 : __expf(v6) - 1.f;
    v7 = v7 > 0.f ? v7 : __expf(v7) - 1.f;
    uint4 qo;
    qo.x = ((unsigned)f2bf(v1) << 16) | (unsigned)f2bf(v0);
    qo.y = ((unsigned)f2bf(v3) << 16) | (unsigned)f2bf(v2);
    qo.z = ((unsigned)f2bf(v5) << 16) | (unsigned)f2bf(v4);
    qo.w = ((unsigned)f2bf(v7) << 16) | (unsigned)f2bf(v6);
    *(uint4*)&out1bf[(size_t)d * 128 + 4 * li] = qo;
}

// ---------------- layer 2 fused: half-wave-per-dst + log_softmax ----------------
// PREFETCH-ALL fast path: all <=8 gather batches (1 dword/lane each) issued before the
// softmax chain -> up to 8 loads in flight per lane, no load->FMA serialization.
// p is SCALAR per edge (single head) so __shfl(p0, j) broadcast is correct here.
// Max subtraction kept. General deg > 32 path: LDS-staged, unchanged.

#define L2_LOADQ(q, jb)                                                         \
    _Pragma("unroll")                                                           \
    for (int k = 0; k < 4; ++k) {                                               \
        int s_ = __shfl(s0, shbase + (jb) + k);                                 \
        q[k] = h2bf[(unsigned)s_ * 32u + li];                                   \
    }

#define L2_FMAQ(q, jb)                                                          \
    _Pragma("unroll")                                                           \
    for (int k = 0; k < 4; ++k) {                                               \
        float A_ = __shfl(p0, shbase + (jb) + k);                               \
        acc0 += A_ * bf_lo(q[k]);                                               \
        acc1 += A_ * bf_hi(q[k]);                                               \
    }

__global__ __launch_bounds__(256) void l2_fused_kernel(const int* __restrict__ off,
                                                       const int2* __restrict__ csr_es,
                                                       const float* __restrict__ a_src,
                                                       const float* __restrict__ a_dst,
                                                       const unsigned* __restrict__ h2bf,
                                                       const float* __restrict__ b2,
                                                       float* __restrict__ out) {
    __shared__ uint2 sp_w[4][2][32];
    int t = threadIdx.x;
    int w = t >> 6, lane = t & 63;
    int half = lane >> 5, li = lane & 31;
    int shbase = half << 5;
    int d = blockIdx.x * 8 + w * 2 + half;
    int beg = off[d], end = off[d + 1];
    int deg = end - beg;
    float ad = a_dst[d];
    int nch = (deg + 31) >> 5;
    int cnt0 = min(deg, 32);
    bool act0 = li < cnt0;

    float sum = 0.f, acc0 = 0.f, acc1 = 0.f;
    float p0 = 0.f;

    if (nch == 1) {
        // ---------- FAST PATH (deg <= 32): prefetch ALL batches ----------
        float el0 = -INFINITY; int s0 = 0;
        if (act0) {
            int2 es = csr_es[beg + li];
            s0 = es.y;
            el0 = leaky(a_src[s0] + ad);
        }
        const int B = (cnt0 + 3) >> 2;     // 1..8
        unsigned q[8][4];
#pragma unroll
        for (int i = 0; i < 8; ++i)
            if (i < B) { L2_LOADQ(q[i], i * 4); }

        float mx = el0;
#pragma unroll
        for (int o = 1; o <= 16; o <<= 1) mx = fmaxf(mx, __shfl_xor(mx, o));
        p0 = __expf(el0 - mx);             // inactive: exp(-inf) = 0
        sum = p0;

#pragma unroll
        for (int i = 0; i < 8; ++i)
            if (i < B) { L2_FMAQ(q[i], i * 4); }
    } else {
        // ---------- GENERAL PATH (deg > 32; rare) ----------
        float mx = -INFINITY;
        for (int cc = 0; cc < nch; ++cc) {
            int idx = beg + cc * 32 + li;
            if (idx < end) {
                int2 es = csr_es[idx];
                mx = fmaxf(mx, leaky(a_src[es.y] + ad));
            }
        }
#pragma unroll
        for (int o = 1; o <= 16; o <<= 1) mx = fmaxf(mx, __shfl_xor(mx, o));
        // merged stage + aggregate with unnormalized p
        for (int cc = 0; cc < nch; ++cc) {
            int idx = beg + cc * 32 + li;
            int cnt = min(32, deg - cc * 32);
            if (idx < end) {
                int2 es = csr_es[idx];
                float el = leaky(a_src[es.y] + ad);
                float p = __expf(el - mx);
                sum += p;
                sp_w[w][half][li] = make_uint2((unsigned)es.y, __float_as_uint(p));
            }
            for (int j = 0; j < cnt; ++j) {
                uint2 e0 = sp_w[w][half][j];
                float A0 = __uint_as_float(e0.y);
                unsigned qv = h2bf[e0.x * 32u + li];
                acc0 += A0 * bf_lo(qv);
                acc1 += A0 * bf_hi(qv);
            }
        }
    }

    // fixed 5-level butterfly all-reduce within half
#pragma unroll
    for (int o = 1; o <= 16; o <<= 1) sum += __shfl_xor(sum, o);
    float inv = 1.f / (sum + EPS_A);
    acc0 *= inv;
    acc1 *= inv;

    bool act = li < 20;
    float v0 = act ? acc0 + b2[2 * li]     : -INFINITY;
    float v1 = act ? acc1 + b2[2 * li + 1] : -INFINITY;
    float mmx = fmaxf(v0, v1);
#pragma unroll
    for (int o = 16; o; o >>= 1) mmx = fmaxf(mmx, __shfl_xor(mmx, o));
    float ex = act ? __expf(v0 - mmx) + __expf(v1 - mmx) : 0.f;
#pragma unroll
    for (int o = 16; o; o >>= 1) ex += __shfl_xor(ex, o);
    float ls = __logf(ex);
    if (act)
        *(float2*)&out[(size_t)d * C2 + 2 * li] = make_float2(v0 - mmx - ls, v1 - mmx - ls);
}

// ---------------- launcher ----------------

extern "C" void kernel_launch(void* const* d_in, const int* in_sizes, int n_in,
                              void* d_out, int out_size, void* d_ws, size_t ws_size,
                              hipStream_t stream) {
    const float* x   = (const float*)d_in[0];
    const int*   ei  = (const int*)d_in[1];
    const float* W1  = (const float*)d_in[2];
    const float* as1 = (const float*)d_in[3];
    const float* ad1 = (const float*)d_in[4];
    const float* b1  = (const float*)d_in[5];
    const float* W2  = (const float*)d_in[6];
    const float* as2 = (const float*)d_in[7];
    const float* ad2 = (const float*)d_in[8];
    const float* b2  = (const float*)d_in[9];

    float* out   = (float*)d_out;
    float* alpha = out + (size_t)N_NODES * C2;    // [ET, 4] final output region

    unsigned* u32    = (unsigned*)d_ws;
    unsigned* h1bf   = u32;                       // 6,400,000 u32 (50000x256 bf16)
    unsigned* xbf    = h1bf + 6400000;            // 6,400,000 u32; ALIASES out1bf
    unsigned* h2bf   = xbf + 6400000;             // 1,600,000 u32 (50000x64 bf16)
    unsigned* w1t    = h2bf + 1600000;            // 32,768 u32
    unsigned* w2t    = w1t + 32768;               // 8,192 u32
    float* a_src1    = (float*)(w2t + 8192);      // 200,000 f (16B-aligned)
    float* a_dst1    = a_src1 + 200000;           // 200,000 f
    float* a_src2    = a_dst1 + 200000;           // 50,000 f
    float* a_dst2    = a_src2 + 50000;            // 50,000 f
    int*   deg       = (int*)(a_dst2 + 50000);    // 50,000 i
    int*   offs      = deg + 50000;               // 50,001 i
    int*   cursor    = offs + 50001;              // 50,000 i
    int*   bsum      = cursor + 50000;            // 256 i + 1 pad
    int2*  csr_es    = (int2*)(bsum + 257);       // 850,000 int2 (8B-aligned)
    unsigned* out1bf = xbf;                       // alias: xbf dead after GEMM1

    const int TB = 256;
    const int EB = (ET + TB - 1) / TB;

    // --- deg = 0 (async memset; graph-capture-safe) ---
    hipMemsetAsync(deg, 0, (size_t)N_NODES * sizeof(int), stream);

    // --- converts + degree histogram (merged; deg pre-zeroed) ---
    convert_all_kernel<<<(CV_TOT + TB - 1) / TB, TB, 0, stream>>>(
        x, W1, W2, ei, (ushort4*)xbf, (unsigned short*)w1t, (unsigned short*)w2t, deg);

    // --- CSR build ---
    scan_block_kernel<<<NSCAN_B, TB, 0, stream>>>(deg, offs, bsum);
    scan_top_kernel<<<1, TB, 0, stream>>>(bsum);
    scan_add_kernel<<<NSCAN_B, TB, 0, stream>>>(offs, cursor, bsum);
    scatter_kernel<<<EB, TB, 0, stream>>>(ei, cursor, csr_es);

    // --- layer 1 ---
    gemm_mfma_kernel<128, 128, 2, 2><<<dim3((N_NODES + 127) / 128, 2), TB, 0, stream>>>(
        (const unsigned short*)xbf, (const unsigned short*)w1t, (unsigned short*)h1bf,
        as1, ad1, a_src1, a_dst1, N_NODES, HC1, 256, H1);
    l1_fused_kernel<<<N_NODES / 8, TB, 0, stream>>>(offs, csr_es,
                                                    (const float4*)a_src1,
                                                    (const float4*)a_dst1,
                                                    h1bf, b1, (float4*)alpha, out1bf);

    // --- layer 2 ---
    gemm_mfma_kernel<256, 64, 4, 1><<<dim3((N_NODES + 255) / 256, 1), TB, 0, stream>>>(
        (const unsigned short*)out1bf, (const unsigned short*)w2t, (unsigned short*)h2bf,
        as2, ad2, a_src2, a_dst2, N_NODES, C2P, C2, 1);
    l2_fused_kernel<<<N_NODES / 8, TB, 0, stream>>>(offs, csr_es, a_src2, a_dst2,
                                                    h2bf, b2, out);
}

// Round 7
// 351.687 us; speedup vs baseline: 1.0204x; 1.0135x over previous
//
#include <hip/hip_runtime.h>
#include <math.h>

#define N_NODES 50000
#define HC1 256      // 4 heads * 64 ch
#define H1 4
#define C2 40
#define C2P 64       // padded
#define E0 800000
#define ET 850000
#define NEG_SLOPE 0.2f
#define EPS_A 1e-16f

typedef __bf16 bf16x8 __attribute__((ext_vector_type(8)));
typedef float f32x4 __attribute__((ext_vector_type(4)));
typedef unsigned short u16x8 __attribute__((ext_vector_type(8)));

// ---------------- bf16 helpers (RNE) ----------------

__device__ inline unsigned short f2bf(float f) {
    unsigned u = __float_as_uint(f);
    return (unsigned short)((u + 0x7FFFu + ((u >> 16) & 1u)) >> 16);
}
__device__ inline float bf_lo(unsigned q) { return __uint_as_float(q << 16); }
__device__ inline float bf_hi(unsigned q) { return __uint_as_float(q & 0xFFFF0000u); }

// ---------------- utility ----------------

__device__ inline int edge_src(const int* __restrict__ ei, int e) {
    return (e < E0) ? ei[e] : (e - E0);
}
__device__ inline int edge_dst(const int* __restrict__ ei, int e) {
    return (e < E0) ? ei[E0 + e] : (e - E0);
}

// 8-channel bf16-pair FMA accumulate
__device__ inline void acc8(float ac[8], float A, uint4 q) {
    ac[0] += A * bf_lo(q.x); ac[1] += A * bf_hi(q.x);
    ac[2] += A * bf_lo(q.y); ac[3] += A * bf_hi(q.y);
    ac[4] += A * bf_lo(q.z); ac[5] += A * bf_hi(q.z);
    ac[6] += A * bf_lo(q.w); ac[7] += A * bf_hi(q.w);
}

__device__ inline float leaky(float v) { return v > 0.f ? v : NEG_SLOPE * v; }

// ------- prep: W1^T->bf16, W2^T(padded)->bf16, + DEGREE HISTOGRAM --------------------
// x is NO LONGER pre-converted: gemm1 reads x (f32) directly and converts during LDS
// staging (saves the 77MB x-convert pass; gemm1's one-column-pass tile reads x once).
// deg[] zeroed by hipMemsetAsync before this kernel.

#define CV_W1 65536
#define CV_W2 16384
#define CV_TOT (CV_W1 + CV_W2 + ET)

__global__ void convert_all_kernel(const float* __restrict__ W1,
                                   const float* __restrict__ W2,
                                   const int* __restrict__ ei,
                                   unsigned short* __restrict__ w1t,
                                   unsigned short* __restrict__ w2t,
                                   int* __restrict__ deg) {
    int tid = blockIdx.x * blockDim.x + threadIdx.x;
    if (tid < CV_W1) {
        int n = tid >> 8, k = tid & 255;
        w1t[tid] = f2bf(W1[k * 256 + n]);
    } else if (tid < CV_W1 + CV_W2) {
        int i = tid - CV_W1;
        int n = i >> 8, k = i & 255;
        w2t[i] = (n < C2) ? f2bf(W2[k * C2 + n]) : (unsigned short)0;
    } else if (tid < CV_TOT) {
        int e = tid - CV_W1 - CV_W2;
        atomicAdd(&deg[edge_dst(ei, e)], 1);
    }
}

// ---------------- CSR build ----------------

__global__ __launch_bounds__(256) void scan_block_kernel(const int* __restrict__ deg,
                                                         int* __restrict__ excl,
                                                         int* __restrict__ bsum) {
    __shared__ int tmp[256];
    int t = threadIdx.x;
    int i = blockIdx.x * 256 + t;
    int v = (i < N_NODES) ? deg[i] : 0;
    tmp[t] = v;
    __syncthreads();
#pragma unroll
    for (int o = 1; o < 256; o <<= 1) {
        int x = (t >= o) ? tmp[t - o] : 0;
        __syncthreads();
        tmp[t] += x;
        __syncthreads();
    }
    if (i < N_NODES) excl[i] = tmp[t] - v;
    if (t == 255) bsum[blockIdx.x] = tmp[255];
}

#define NSCAN_B 196   // ceil(50000/256)

__global__ __launch_bounds__(256) void scan_top_kernel(int* __restrict__ bsum) {
    __shared__ int tmp[256];
    int t = threadIdx.x;
    int v = (t < NSCAN_B) ? bsum[t] : 0;
    tmp[t] = v;
    __syncthreads();
#pragma unroll
    for (int o = 1; o < 256; o <<= 1) {
        int x = (t >= o) ? tmp[t - o] : 0;
        __syncthreads();
        tmp[t] += x;
        __syncthreads();
    }
    if (t < NSCAN_B) bsum[t] = tmp[t] - v;   // exclusive
}

__global__ __launch_bounds__(256) void scan_add_kernel(int* __restrict__ offsets,
                                                       int* __restrict__ cursor,
                                                       const int* __restrict__ bsum) {
    int i = blockIdx.x * 256 + threadIdx.x;
    if (i < N_NODES) {
        int v = offsets[i] + bsum[blockIdx.x];
        offsets[i] = v;
        cursor[i] = v;
    }
    if (i == 0) offsets[N_NODES] = ET;
}

// writes (edge id, src id) as one int2 in CSR order
__global__ void scatter_kernel(const int* __restrict__ ei, int* __restrict__ cursor,
                               int2* __restrict__ csr_es) {
    int e = blockIdx.x * blockDim.x + threadIdx.x;
    if (e >= ET) return;
    int d = edge_dst(ei, e);
    int pos = atomicAdd(&cursor[d], 1);
    csr_es[pos] = make_int2(e, edge_src(ei, e));
}

// ---------------- MFMA GEMM + attention-dot epilogue ----------------
// Cbf[M,Nc] = bf16( A[M,256] * Bt[Nc,256]^T ); K = 256.
// AF32=true: A is f32 and converted to bf16 during LDS staging (kills the xbf pass).
// DOUBLE-BUFFERED LDS: one barrier per 32-wide K-step.
// Epilogue: a_src_o[row*hstride+head] = sum_col acc*att_s[col] (head = wave col-base/64).
// Wave tile 64x64 (4x4 of 16x16x32 mfma). LDS stride 40 bf16 -> 2-way aliasing (free).

#define GEMM_STAGE(k0v, bufv)                                                     \
    _Pragma("unroll")                                                             \
    for (int i = 0; i < TBM / 64; ++i) {                                          \
        int idx = t + i * 256;                                                    \
        int row = idx >> 2, seg = idx & 3;                                        \
        u16x8 v = {};                                                             \
        if (bm + row < M) {                                                       \
            if constexpr (AF32) {                                                 \
                const float* sp = Af32 + (size_t)(bm + row) * 256 + (k0v) + seg * 8; \
                float4 f0 = *(const float4*)sp;                                   \
                float4 f1 = *(const float4*)(sp + 4);                             \
                v[0] = f2bf(f0.x); v[1] = f2bf(f0.y);                             \
                v[2] = f2bf(f0.z); v[3] = f2bf(f0.w);                             \
                v[4] = f2bf(f1.x); v[5] = f2bf(f1.y);                             \
                v[6] = f2bf(f1.z); v[7] = f2bf(f1.w);                             \
            } else {                                                              \
                v = *(const u16x8*)(Abf + (size_t)(bm + row) * 256 + (k0v) + seg * 8); \
            }                                                                     \
        }                                                                         \
        *(u16x8*)&As[bufv][row * LDK + seg * 8] = v;                              \
    }                                                                             \
    _Pragma("unroll")                                                             \
    for (int i = 0; i < TBN / 64; ++i) {                                          \
        int idx = t + i * 256;                                                    \
        int row = idx >> 2, seg = idx & 3;                                        \
        u16x8 v = *(const u16x8*)(Bt + (size_t)(bn + row) * 256 + (k0v) + seg * 8); \
        *(u16x8*)&Bs[bufv][row * LDK + seg * 8] = v;                              \
    }

template <int TBM, int TBN, int WROWS, int WCOLS, bool AF32>
__global__ __launch_bounds__(256) void gemm_mfma_kernel(const unsigned short* __restrict__ Abf,
                                                        const float* __restrict__ Af32,
                                                        const unsigned short* __restrict__ Bt,
                                                        unsigned short* __restrict__ Cbf,
                                                        const float* __restrict__ att_s,
                                                        const float* __restrict__ att_d,
                                                        float* __restrict__ a_src_o,
                                                        float* __restrict__ a_dst_o,
                                                        int M, int Nc, int attN, int hstride) {
    static_assert(TBM == WROWS * 64 && TBN == WCOLS * 64, "tile");
    constexpr int LDK = 40;
    __shared__ alignas(16) unsigned short As[2][TBM * LDK];
    __shared__ alignas(16) unsigned short Bs[2][TBN * LDK];
    const int t = threadIdx.x;
    const int lane = t & 63;
    const int w = t >> 6;
    const int quad = lane >> 4;
    const int l16 = lane & 15;
    const int wm = (w / WCOLS) * 64;
    const int wn = (w % WCOLS) * 64;
    const int bm = blockIdx.x * TBM;
    const int bn = blockIdx.y * TBN;

    f32x4 acc[4][4] = {};

    GEMM_STAGE(0, 0);
    int cur = 0;
    for (int k0 = 0; k0 < 256; k0 += 32) {
        __syncthreads();   // staging of buf[cur] visible; prior reads of buf[cur^1] done
        if (k0 + 32 < 256) { GEMM_STAGE(k0 + 32, cur ^ 1); }

        bf16x8 af[4], bfr[4];
#pragma unroll
        for (int mi = 0; mi < 4; ++mi)
            af[mi] = *(const bf16x8*)&As[cur][(wm + mi * 16 + l16) * LDK + quad * 8];
#pragma unroll
        for (int ni = 0; ni < 4; ++ni)
            bfr[ni] = *(const bf16x8*)&Bs[cur][(wn + ni * 16 + l16) * LDK + quad * 8];
#pragma unroll
        for (int mi = 0; mi < 4; ++mi)
#pragma unroll
            for (int ni = 0; ni < 4; ++ni)
                acc[mi][ni] = __builtin_amdgcn_mfma_f32_16x16x32_bf16(
                    af[mi], bfr[ni], acc[mi][ni], 0, 0, 0);
        cur ^= 1;
    }

    // C/D layout: col = lane&15, row = quad*4 + r
#pragma unroll
    for (int mi = 0; mi < 4; ++mi)
#pragma unroll
        for (int ni = 0; ni < 4; ++ni)
#pragma unroll
            for (int r = 0; r < 4; ++r) {
                int row = bm + wm + mi * 16 + quad * 4 + r;
                int col = bn + wn + ni * 16 + l16;
                if (row < M)
                    Cbf[(size_t)row * Nc + col] = f2bf(acc[mi][ni][r]);
            }

    // ---- attention-dot epilogue ----
    float asc[4], adc[4];
#pragma unroll
    for (int ni = 0; ni < 4; ++ni) {
        int col = bn + wn + ni * 16 + l16;
        bool valid = col < attN;
        asc[ni] = valid ? att_s[col] : 0.f;
        adc[ni] = valid ? att_d[col] : 0.f;
    }
    float vs[16], vd[16];
#pragma unroll
    for (int mi = 0; mi < 4; ++mi)
#pragma unroll
        for (int r = 0; r < 4; ++r) {
            float s = 0.f, dd = 0.f;
#pragma unroll
            for (int ni = 0; ni < 4; ++ni) {
                s += acc[mi][ni][r] * asc[ni];
                dd += acc[mi][ni][r] * adc[ni];
            }
            vs[mi * 4 + r] = s;
            vd[mi * 4 + r] = dd;
        }
    // butterfly all-reduce across l16: lane l16 ends holding row i = l16 (i = mi*4+r)
#pragma unroll
    for (int k = 0; k < 4; ++k) {
        const int o = 1 << k;
        const int b = (l16 >> k) & 1;
#pragma unroll
        for (int j = 0; j < (8 >> k); ++j) {
            float lo = vs[2 * j], hi = vs[2 * j + 1];
            float keep = b ? hi : lo, send = b ? lo : hi;
            vs[j] = keep + __shfl_xor(send, o);
            lo = vd[2 * j]; hi = vd[2 * j + 1];
            keep = b ? hi : lo; send = b ? lo : hi;
            vd[j] = keep + __shfl_xor(send, o);
        }
    }
    {
        int mi = l16 >> 2, r = l16 & 3;
        int row = bm + wm + mi * 16 + quad * 4 + r;
        int head = (bn + wn) >> 6;
        if (row < M) {
            a_src_o[(size_t)row * hstride + head] = vs[0];
            a_dst_o[(size_t)row * hstride + head] = vd[0];
        }
    }
}

// ---------------- layer 1 fused: half-wave-per-dst softmax (4 heads) + aggregation ------
// AT MEMORY-MIX ROOFLINE (r5/r6: ~495MB delivered in ~81us; FETCH pinned at 216MB across
// three structurally different variants). Kept exactly as the round-5/6 verified version.

#define L1_LOADQ(q, jb)                                                         \
    _Pragma("unroll")                                                           \
    for (int k = 0; k < 4; ++k) {                                               \
        int s_ = __shfl(esy, shbase + (jb) + k);                                \
        q[k] = *(const uint4*)&h1bf[(unsigned)s_ * 128u + 4u * li];             \
    }

#define L1_FMAQ(q, jb)                                                          \
    _Pragma("unroll")                                                           \
    for (int k = 0; k < 4; ++k) {                                               \
        float A_ = aw[4 * ((jb) + k) + headc];                                  \
        acc8(ac, A_, q[k]);                                                     \
    }

__global__ __launch_bounds__(256) void l1_fused_kernel(const int* __restrict__ off,
                                                       const int2* __restrict__ csr_es,
                                                       const float4* __restrict__ a_src4,
                                                       const float4* __restrict__ a_dst4,
                                                       const unsigned* __restrict__ h1bf,
                                                       const float* __restrict__ b1,
                                                       float4* __restrict__ alpha_out4,
                                                       unsigned* __restrict__ out1bf) {
    __shared__ int    s_w[4][2][32];
    __shared__ float4 p_w[4][2][32];
    int t = threadIdx.x;
    int w = t >> 6, lane = t & 63;
    int half = lane >> 5, li = lane & 31;
    int shbase = half << 5;
    int d = blockIdx.x * 8 + w * 2 + half;   // 50000 = 6250*8, always valid
    int beg = off[d], end = off[d + 1];
    int deg = end - beg;
    int nch = (deg + 31) >> 5;
    int cnt0 = min(deg, 32);
    bool act0 = li < cnt0;
    float4 ad4 = a_dst4[d];
    int headc = li >> 3;

    float ac[8] = {};
    float4 sum = make_float4(0.f, 0.f, 0.f, 0.f);
    float4 mx = make_float4(-INFINITY, -INFINITY, -INFINITY, -INFINITY);
    int2 es0 = make_int2(0, 0);
    float4 p0 = make_float4(0.f, 0.f, 0.f, 0.f);

    const float* aw = (const float*)&p_w[w][half][0];
    const int*   sw = &s_w[w][half][0];

    if (nch == 1) {
        // ---------- FAST PATH (deg <= 32) ----------
        float4 l0 = make_float4(-INFINITY, -INFINITY, -INFINITY, -INFINITY);
        float4 as4 = make_float4(0.f, 0.f, 0.f, 0.f);
        if (act0) {
            es0 = csr_es[beg + li];
            as4 = a_src4[es0.y];               // issued first (feeds softmax chain)
        }
        int esy = es0.y;                       // 0 on inactive lanes -> safe row 0
        const int B = (cnt0 + 3) >> 2;         // 4-edge batches, >= 1 (self-loop)

        // prefetch batches 0 and 1 NOW - they fly under the whole softmax phase
        uint4 qa[4], qb[4];
        L1_LOADQ(qa, 0);
        if (B > 1) { L1_LOADQ(qb, 4); }

        if (act0) {
            l0.x = leaky(as4.x + ad4.x);
            l0.y = leaky(as4.y + ad4.y);
            l0.z = leaky(as4.z + ad4.z);
            l0.w = leaky(as4.w + ad4.w);
        }
        // fixed 5-level max butterfly (inactive lanes hold -inf)
        mx = l0;
#pragma unroll
        for (int o = 1; o <= 16; o <<= 1) {
            mx.x = fmaxf(mx.x, __shfl_xor(mx.x, o));
            mx.y = fmaxf(mx.y, __shfl_xor(mx.y, o));
            mx.z = fmaxf(mx.z, __shfl_xor(mx.z, o));
            mx.w = fmaxf(mx.w, __shfl_xor(mx.w, o));
        }
        // p in [0,1]; inactive lanes: exp(-inf - finite) = 0
        p0.x = __expf(l0.x - mx.x);
        p0.y = __expf(l0.y - mx.y);
        p0.z = __expf(l0.z - mx.z);
        p0.w = __expf(l0.w - mx.w);
        p_w[w][half][li] = p0;                 // stage (inactive lanes store zeros)
        sum = p0;

        // ---- 2-stage pipelined aggregation ----
        int i = 0;
        for (; i + 2 <= B; i += 2) {
            L1_FMAQ(qa, i * 4);
            if (i + 2 < B) { L1_LOADQ(qa, (i + 2) * 4); }
            L1_FMAQ(qb, i * 4 + 4);
            if (i + 3 < B) { L1_LOADQ(qb, (i + 3) * 4); }
        }
        if (i < B) { L1_FMAQ(qa, i * 4); }
    } else {
        // ---------- GENERAL PATH pass A1: max (deg > 32; rare) ----------
        for (int cc = 0; cc < nch; ++cc) {
            int idx = beg + cc * 32 + li;
            if (idx < end) {
                int2 es = csr_es[idx];
                float4 as4 = a_src4[es.y];
                mx.x = fmaxf(mx.x, leaky(as4.x + ad4.x));
                mx.y = fmaxf(mx.y, leaky(as4.y + ad4.y));
                mx.z = fmaxf(mx.z, leaky(as4.z + ad4.z));
                mx.w = fmaxf(mx.w, leaky(as4.w + ad4.w));
            }
        }
#pragma unroll
        for (int o = 1; o <= 16; o <<= 1) {
            mx.x = fmaxf(mx.x, __shfl_xor(mx.x, o));
            mx.y = fmaxf(mx.y, __shfl_xor(mx.y, o));
            mx.z = fmaxf(mx.z, __shfl_xor(mx.z, o));
            mx.w = fmaxf(mx.w, __shfl_xor(mx.w, o));
        }
        // ---------- pass A2: sum ----------
        for (int cc = 0; cc < nch; ++cc) {
            int idx = beg + cc * 32 + li;
            if (idx < end) {
                int2 es = csr_es[idx];
                float4 as4 = a_src4[es.y];
                sum.x += __expf(leaky(as4.x + ad4.x) - mx.x);
                sum.y += __expf(leaky(as4.y + ad4.y) - mx.y);
                sum.z += __expf(leaky(as4.z + ad4.z) - mx.z);
                sum.w += __expf(leaky(as4.w + ad4.w) - mx.w);
            }
        }
    }

    // fixed 5-level butterfly all-reduce within the 32-lane half
#pragma unroll
    for (int o = 1; o <= 16; o <<= 1) {
        sum.x += __shfl_xor(sum.x, o);
        sum.y += __shfl_xor(sum.y, o);
        sum.z += __shfl_xor(sum.z, o);
        sum.w += __shfl_xor(sum.w, o);
    }
    float4 inv;
    inv.x = 1.f / (sum.x + EPS_A); inv.y = 1.f / (sum.y + EPS_A);
    inv.z = 1.f / (sum.z + EPS_A); inv.w = 1.f / (sum.w + EPS_A);
    float invh = (headc == 0) ? inv.x : (headc == 1) ? inv.y
               : (headc == 2) ? inv.z : inv.w;

    if (nch == 1) {
        if (act0) {
            float4 al0;
            al0.x = p0.x * inv.x; al0.y = p0.y * inv.y;
            al0.z = p0.z * inv.z; al0.w = p0.w * inv.w;
            alpha_out4[es0.x] = al0;
        }
    } else {
        // ---------- GENERAL PATH pass B: stage + aggregate + alpha ----------
        for (int cc = 0; cc < nch; ++cc) {
            int idx = beg + cc * 32 + li;
            int cnt = min(32, deg - cc * 32);
            if (idx < end) {
                int2 es = csr_es[idx];
                float4 as4 = a_src4[es.y];
                float4 p;
                p.x = __expf(leaky(as4.x + ad4.x) - mx.x);
                p.y = __expf(leaky(as4.y + ad4.y) - mx.y);
                p.z = __expf(leaky(as4.z + ad4.z) - mx.z);
                p.w = __expf(leaky(as4.w + ad4.w) - mx.w);
                float4 al;
                al.x = p.x * inv.x; al.y = p.y * inv.y;
                al.z = p.z * inv.z; al.w = p.w * inv.w;
                alpha_out4[es.x] = al;
                s_w[w][half][li] = es.y;
                p_w[w][half][li] = p;       // UNNORMALIZED
            }
            for (int j = 0; j < cnt; ++j) {
                int s = sw[j];
                float A = aw[4 * j + headc];
                uint4 q = *(const uint4*)&h1bf[(unsigned)s * 128u + 4u * li];
                acc8(ac, A, q);
            }
        }
    }

#pragma unroll
    for (int c = 0; c < 8; ++c) ac[c] *= invh;

    // ---- epilogue: bias + ELU -> bf16 packed (each half writes its own dst) ----
    float4 bb0 = *(const float4*)&b1[8 * li];
    float4 bb1 = *(const float4*)&b1[8 * li + 4];
    float v0 = ac[0] + bb0.x, v1 = ac[1] + bb0.y;
    float v2 = ac[2] + bb0.z, v3 = ac[3] + bb0.w;
    float v4 = ac[4] + bb1.x, v5 = ac[5] + bb1.y;
    float v6 = ac[6] + bb1.z, v7 = ac[7] + bb1.w;
    v0 = v0 > 0.f ? v0 : __expf(v0) - 1.f;
    v1 = v1 > 0.f ? v1 : __expf(v1) - 1.f;
    v2 = v2 > 0.f ? v2 : __expf(v2) - 1.f;
    v3 = v3 > 0.f ? v3 : __expf(v3) - 1.f;
    v4 = v4 > 0.f ? v4 : __expf(v4) - 1.f;
    v5 = v5 > 0.f ? v5 : __expf(v5) - 1.f;
    v6 = v6 > 0.f ? v6 : __expf(v6) - 1.f;
    v7 = v7 > 0.f ? v7 : __expf(v7) - 1.f;
    uint4 qo;
    qo.x = ((unsigned)f2bf(v1) << 16) | (unsigned)f2bf(v0);
    qo.y = ((unsigned)f2bf(v3) << 16) | (unsigned)f2bf(v2);
    qo.z = ((unsigned)f2bf(v5) << 16) | (unsigned)f2bf(v4);
    qo.w = ((unsigned)f2bf(v7) << 16) | (unsigned)f2bf(v6);
    *(uint4*)&out1bf[(size_t)d * 128 + 4 * li] = qo;
}

// ---------------- layer 2 fused: half-wave-per-dst + log_softmax ----------------
// PREFETCH-ALL fast path: all <=8 gather batches issued before the softmax chain.
// p is SCALAR per edge (single head) so __shfl(p0, j) broadcast is correct here.

#define L2_LOADQ(q, jb)                                                         \
    _Pragma("unroll")                                                           \
    for (int k = 0; k < 4; ++k) {                                               \
        int s_ = __shfl(s0, shbase + (jb) + k);                                 \
        q[k] = h2bf[(unsigned)s_ * 32u + li];                                   \
    }

#define L2_FMAQ(q, jb)                                                          \
    _Pragma("unroll")                                                           \
    for (int k = 0; k < 4; ++k) {                                               \
        float A_ = __shfl(p0, shbase + (jb) + k);                               \
        acc0 += A_ * bf_lo(q[k]);                                               \
        acc1 += A_ * bf_hi(q[k]);                                               \
    }

__global__ __launch_bounds__(256) void l2_fused_kernel(const int* __restrict__ off,
                                                       const int2* __restrict__ csr_es,
                                                       const float* __restrict__ a_src,
                                                       const float* __restrict__ a_dst,
                                                       const unsigned* __restrict__ h2bf,
                                                       const float* __restrict__ b2,
                                                       float* __restrict__ out) {
    __shared__ uint2 sp_w[4][2][32];
    int t = threadIdx.x;
    int w = t >> 6, lane = t & 63;
    int half = lane >> 5, li = lane & 31;
    int shbase = half << 5;
    int d = blockIdx.x * 8 + w * 2 + half;
    int beg = off[d], end = off[d + 1];
    int deg = end - beg;
    float ad = a_dst[d];
    int nch = (deg + 31) >> 5;
    int cnt0 = min(deg, 32);
    bool act0 = li < cnt0;

    float sum = 0.f, acc0 = 0.f, acc1 = 0.f;
    float p0 = 0.f;

    if (nch == 1) {
        // ---------- FAST PATH (deg <= 32): prefetch ALL batches ----------
        float el0 = -INFINITY; int s0 = 0;
        if (act0) {
            int2 es = csr_es[beg + li];
            s0 = es.y;
            el0 = leaky(a_src[s0] + ad);
        }
        const int B = (cnt0 + 3) >> 2;     // 1..8
        unsigned q[8][4];
#pragma unroll
        for (int i = 0; i < 8; ++i)
            if (i < B) { L2_LOADQ(q[i], i * 4); }

        float mx = el0;
#pragma unroll
        for (int o = 1; o <= 16; o <<= 1) mx = fmaxf(mx, __shfl_xor(mx, o));
        p0 = __expf(el0 - mx);             // inactive: exp(-inf) = 0
        sum = p0;

#pragma unroll
        for (int i = 0; i < 8; ++i)
            if (i < B) { L2_FMAQ(q[i], i * 4); }
    } else {
        // ---------- GENERAL PATH (deg > 32; rare) ----------
        float mx = -INFINITY;
        for (int cc = 0; cc < nch; ++cc) {
            int idx = beg + cc * 32 + li;
            if (idx < end) {
                int2 es = csr_es[idx];
                mx = fmaxf(mx, leaky(a_src[es.y] + ad));
            }
        }
#pragma unroll
        for (int o = 1; o <= 16; o <<= 1) mx = fmaxf(mx, __shfl_xor(mx, o));
        // merged stage + aggregate with unnormalized p
        for (int cc = 0; cc < nch; ++cc) {
            int idx = beg + cc * 32 + li;
            int cnt = min(32, deg - cc * 32);
            if (idx < end) {
                int2 es = csr_es[idx];
                float el = leaky(a_src[es.y] + ad);
                float p = __expf(el - mx);
                sum += p;
                sp_w[w][half][li] = make_uint2((unsigned)es.y, __float_as_uint(p));
            }
            for (int j = 0; j < cnt; ++j) {
                uint2 e0 = sp_w[w][half][j];
                float A0 = __uint_as_float(e0.y);
                unsigned qv = h2bf[e0.x * 32u + li];
                acc0 += A0 * bf_lo(qv);
                acc1 += A0 * bf_hi(qv);
            }
        }
    }

    // fixed 5-level butterfly all-reduce within half
#pragma unroll
    for (int o = 1; o <= 16; o <<= 1) sum += __shfl_xor(sum, o);
    float inv = 1.f / (sum + EPS_A);
    acc0 *= inv;
    acc1 *= inv;

    bool act = li < 20;
    float v0 = act ? acc0 + b2[2 * li]     : -INFINITY;
    float v1 = act ? acc1 + b2[2 * li + 1] : -INFINITY;
    float mmx = fmaxf(v0, v1);
#pragma unroll
    for (int o = 16; o; o >>= 1) mmx = fmaxf(mmx, __shfl_xor(mmx, o));
    float ex = act ? __expf(v0 - mmx) + __expf(v1 - mmx) : 0.f;
#pragma unroll
    for (int o = 16; o; o >>= 1) ex += __shfl_xor(ex, o);
    float ls = __logf(ex);
    if (act)
        *(float2*)&out[(size_t)d * C2 + 2 * li] = make_float2(v0 - mmx - ls, v1 - mmx - ls);
}

// ---------------- launcher ----------------

extern "C" void kernel_launch(void* const* d_in, const int* in_sizes, int n_in,
                              void* d_out, int out_size, void* d_ws, size_t ws_size,
                              hipStream_t stream) {
    const float* x   = (const float*)d_in[0];
    const int*   ei  = (const int*)d_in[1];
    const float* W1  = (const float*)d_in[2];
    const float* as1 = (const float*)d_in[3];
    const float* ad1 = (const float*)d_in[4];
    const float* b1  = (const float*)d_in[5];
    const float* W2  = (const float*)d_in[6];
    const float* as2 = (const float*)d_in[7];
    const float* ad2 = (const float*)d_in[8];
    const float* b2  = (const float*)d_in[9];

    float* out   = (float*)d_out;
    float* alpha = out + (size_t)N_NODES * C2;    // [ET, 4] final output region

    unsigned* u32    = (unsigned*)d_ws;
    unsigned* h1bf   = u32;                       // 6,400,000 u32 (50000x256 bf16)
    unsigned* out1bf = h1bf + 6400000;            // 6,400,000 u32 (50000x256 bf16)
    unsigned* h2bf   = out1bf + 6400000;          // 1,600,000 u32 (50000x64 bf16)
    unsigned* w1t    = h2bf + 1600000;            // 32,768 u32
    unsigned* w2t    = w1t + 32768;               // 8,192 u32
    float* a_src1    = (float*)(w2t + 8192);      // 200,000 f (16B-aligned)
    float* a_dst1    = a_src1 + 200000;           // 200,000 f
    float* a_src2    = a_dst1 + 200000;           // 50,000 f
    float* a_dst2    = a_src2 + 50000;            // 50,000 f
    int*   deg       = (int*)(a_dst2 + 50000);    // 50,000 i
    int*   offs      = deg + 50000;               // 50,001 i
    int*   cursor    = offs + 50001;              // 50,000 i
    int*   bsum      = cursor + 50000;            // 256 i + 1 pad
    int2*  csr_es    = (int2*)(bsum + 257);       // 850,000 int2 (8B-aligned)

    const int TB = 256;
    const int EB = (ET + TB - 1) / TB;

    // --- deg = 0 (async memset; graph-capture-safe) ---
    hipMemsetAsync(deg, 0, (size_t)N_NODES * sizeof(int), stream);

    // --- W converts + degree histogram (x no longer pre-converted) ---
    convert_all_kernel<<<(CV_TOT + TB - 1) / TB, TB, 0, stream>>>(
        W1, W2, ei, (unsigned short*)w1t, (unsigned short*)w2t, deg);

    // --- CSR build ---
    scan_block_kernel<<<NSCAN_B, TB, 0, stream>>>(deg, offs, bsum);
    scan_top_kernel<<<1, TB, 0, stream>>>(bsum);
    scan_add_kernel<<<NSCAN_B, TB, 0, stream>>>(offs, cursor, bsum);
    scatter_kernel<<<EB, TB, 0, stream>>>(ei, cursor, csr_es);

    // --- layer 1: GEMM reads x (f32) directly, one column pass (TBN=256) ---
    gemm_mfma_kernel<64, 256, 1, 4, true><<<dim3((N_NODES + 63) / 64, 1), TB, 0, stream>>>(
        nullptr, x, (const unsigned short*)w1t, (unsigned short*)h1bf,
        as1, ad1, a_src1, a_dst1, N_NODES, HC1, 256, H1);
    l1_fused_kernel<<<N_NODES / 8, TB, 0, stream>>>(offs, csr_es,
                                                    (const float4*)a_src1,
                                                    (const float4*)a_dst1,
                                                    h1bf, b1, (float4*)alpha, out1bf);

    // --- layer 2 ---
    gemm_mfma_kernel<256, 64, 4, 1, false><<<dim3((N_NODES + 255) / 256, 1), TB, 0, stream>>>(
        (const unsigned short*)out1bf, nullptr, (const unsigned short*)w2t,
        (unsigned short*)h2bf, as2, ad2, a_src2, a_dst2, N_NODES, C2P, C2, 1);
    l2_fused_kernel<<<N_NODES / 8, TB, 0, stream>>>(offs, csr_es, a_src2, a_dst2,
                                                    h2bf, b2, out);
}